// Round 4
// baseline (1750.126 us; speedup 1.0000x reference)
//
#include <hip/hip_runtime.h>

#define Q_LBF 1e-4f
#define DTF   3600.0f
#define NN    131071

#if __has_builtin(__builtin_amdgcn_exp2f)
#define FEXP2(x) __builtin_amdgcn_exp2f(x)
#else
#define FEXP2(x) exp2f(x)
#endif
#if __has_builtin(__builtin_amdgcn_logf)
#define FLOG2(x) __builtin_amdgcn_logf(x)
#else
#define FLOG2(x) log2f(x)
#endif
#if __has_builtin(__builtin_amdgcn_rcpf)
#define FRCP(x) __builtin_amdgcn_rcpf(x)
#else
#define FRCP(x) (1.0f/(x))
#endif

// Per-node time-invariant constants (everything except q folded once).
struct NC { float a1, e, tw, ssd, w2, a2, kd, kx; };

__device__ __forceinline__ NC make_nc(const float* __restrict__ nr,
                                      const float* __restrict__ qsr,
                                      const float* __restrict__ len,
                                      const float* __restrict__ slp,
                                      const float* __restrict__ twp,
                                      const float* __restrict__ ssp,
                                      const float* __restrict__ xsp,
                                      int g) {
  float n  = fmaf(nr[g], 0.34f, 0.01f);
  float qs = 3.0f * qsr[g];
  float s0 = fmaxf(slp[g], 1e-4f);
  float rs = sqrtf(s0);
  float L  = len[g];
  float x  = xsp[g];
  float ss = ssp[g];
  NC c;
  c.a1  = n * (qs + 1.0f) / fmaf(21.0f, rs, 1e-8f);
  c.e   = 3.0f / fmaf(3.0f, qs, 5.0f);
  c.tw  = twp[g];
  c.ssd = 2.0f * ss;
  c.w2  = 2.0f * sqrtf(fmaf(ss, ss, 1.0f));
  c.a2  = rs / n;
  float kl = 1.2f * L;
  c.kd  = kl * (1.0f - x);
  c.kx  = kl * x;
  return c;
}

__device__ __forceinline__ float node_b(const NC& c, float q, float qpc, float it,
                                        float& c1o) {
  float z    = q * c.a1;
  float d    = fmaxf(FEXP2(c.e * FLOG2(z)), 0.01f);
  float bot  = fmaxf(fmaf(-c.ssd, d, c.tw), 0.1f);
  float area = (c.tw + bot) * (0.5f * d);
  float wet  = fmaf(c.w2, d, bot);
  float R    = area * FRCP(wet);
  float v2   = c.a2 * FEXP2(0.66666668f * FLOG2(R));
  v2 = fminf(fmaxf(v2, 0.3f), 15.0f);
  float rv   = FRCP(v2);
  float rden = FRCP(fmaf(c.kd, rv, DTF));
  float c2   = fmaf(c.kx, rv, DTF) * rden;
  float c4   = 7200.0f * rden;
  c1o = c4 - c2;
  float c3 = 1.0f - c4;
  return fmaf(c2, it, fmaf(c3, q, c4 * qpc));
}

__device__ __forceinline__ int iclamp(int v, int lo, int hi) {
  return v < lo ? lo : (v > hi ? hi : v);
}

// Cross-XCD producer/consumer sync (per-XCD L2 non-coherent):
// publish = RELEASE atomicAdd (drains stores + L2 writeback before flag);
// spin    = relaxed agent-scope polls, then one ACQUIRE-ordered load
//           (+ agent acquire fence where the builtin exists) to invalidate
//           stale L1/L2 lines before touching the data.
__device__ __forceinline__ void publish(unsigned* p) {
  __hip_atomic_fetch_add(p, 1u, __ATOMIC_RELEASE, __HIP_MEMORY_SCOPE_AGENT);
}
__device__ __forceinline__ void spin_ge(unsigned* p, unsigned tgt) {
  while (__hip_atomic_load(p, __ATOMIC_RELAXED, __HIP_MEMORY_SCOPE_AGENT) < tgt) {
    __builtin_amdgcn_s_sleep(2);
  }
  (void)__hip_atomic_load(p, __ATOMIC_ACQUIRE, __HIP_MEMORY_SCOPE_AGENT);
#if __has_builtin(__builtin_amdgcn_fence)
  __builtin_amdgcn_fence(__ATOMIC_ACQUIRE, "agent");
#endif
}

// ---- role A: levels 0..6, one depth-7 subtree per wave (1024 waves) ----
__device__ __forceinline__ void run_A(
    const float* __restrict__ qp,
    const float* __restrict__ nr, const float* __restrict__ qsr,
    const float* __restrict__ len, const float* __restrict__ slp,
    const float* __restrict__ twp, const float* __restrict__ ssp,
    const float* __restrict__ xsp,
    float* __restrict__ S1, unsigned* __restrict__ F1, int wv, int lane) {
  const int g_leaf = (wv << 6) + lane;
  int e, g_int, cs0;
  if (lane < 32)      { e = 1; g_int = 65536  + (wv << 5) + lane;        cs0 = 2*lane; }
  else if (lane < 48) { e = 2; g_int = 98304  + (wv << 4) + (lane - 32); cs0 = 2*(lane-32); }
  else if (lane < 56) { e = 3; g_int = 114688 + (wv << 3) + (lane - 48); cs0 = 32 + 2*(lane-48); }
  else if (lane < 60) { e = 4; g_int = 122880 + (wv << 2) + (lane - 56); cs0 = 48 + 2*(lane-56); }
  else if (lane < 62) { e = 5; g_int = 126976 + (wv << 1) + (lane - 60); cs0 = 56 + 2*(lane-60); }
  else                { e = 6; g_int = 129024 + wv;                      cs0 = 60; }
  NC cL = make_nc(nr,qsr,len,slp,twp,ssp,xsp, g_leaf);
  NC cI = make_nc(nr,qsr,len,slp,twp,ssp,xsp, g_int);
  float q0L = qp[g_leaf];
  float q0I = qp[g_int];
  float iLa = __shfl(q0L, cs0), iLb = __shfl(q0L, cs0 + 1);
  float iIa = __shfl(q0I, cs0), iIb = __shfl(q0I, cs0 + 1);
  const bool l1 = (e == 1);
  const float itInit = l1 ? (iLa + iLb) : (iIa + iIb);   // raw children q0 (t=0 i_t)
  if (lane == 62) S1[wv] = q0I;
  float qcL = q0L, qcI = q0I, ulL = q0L, ulI = q0I;
  float pu0 = 0.0f, pu1 = 0.0f;
  float rgL[4], rgI[4];
#pragma unroll
  for (int j = 0; j < 4; ++j) {
    rgL[j] = qp[iclamp(j,     0, 335) * NN + g_leaf];
    rgI[j] = qp[iclamp(j - e, 0, 335) * NN + g_int];
  }
  unsigned* fslot = F1 + (wv >> 6) * 42;
#pragma unroll 4
  for (int s = 0; s < 344; ++s) {
    float guL0 = __shfl(ulL, cs0), guL1 = __shfl(ulL, cs0 + 1);
    float guI0 = __shfl(ulI, cs0), guI1 = __shfl(ulI, cs0 + 1);
    float u0 = l1 ? guL0 : guI0;
    float u1 = l1 ? guL1 : guI1;
    // children state at t = clamp(u gathered LAST iter); t=0 case precomputed
    float it = (s == e) ? itInit : (fmaxf(pu0, Q_LBF) + fmaxf(pu1, Q_LBF));
    if (s == e) qcI = q0I;                     // epoch start: raw q_prime[0]
    float qpcL = fmaxf(rgL[s & 3], Q_LBF);
    float qpcI = fmaxf(rgI[s & 3], Q_LBF);
    float c1l, c1i;
    float bL = node_b(cL, qcL, qpcL, 0.0f, c1l);
    float bI = node_b(cI, qcI, qpcI, it,   c1i);
    float uIn = fmaf(c1i, u0 + u1, bI);        // shuffle result consumed LAST
    qcL = fmaxf(bL,  Q_LBF); ulL = bL;
    qcI = fmaxf(uIn, Q_LBF); ulI = uIn;
    pu0 = u0; pu1 = u1;
    if (lane == 62 && s >= 6 && s <= 340) S1[(s - 5) * 1024 + wv] = uIn;
    if ((s & 7) == 4 && s >= 12) {             // after row 8c+7: publish chunk c
      if (lane == 62) publish(fslot + ((s - 12) >> 3));
    }
    rgL[s & 3] = qp[iclamp(s + 4,     0, 335) * NN + g_leaf];
    rgI[s & 3] = qp[iclamp(s + 4 - e, 0, 335) * NN + g_int];
  }
}

// ---- role B: levels 7..12, 16 waves, consumes S1 stream, produces S2 ----
__device__ __forceinline__ void run_B(
    const float* __restrict__ qp,
    const float* __restrict__ nr, const float* __restrict__ qsr,
    const float* __restrict__ len, const float* __restrict__ slp,
    const float* __restrict__ twp, const float* __restrict__ ssp,
    const float* __restrict__ xsp,
    const float* __restrict__ S1, float* __restrict__ S2,
    unsigned* __restrict__ F1, unsigned* __restrict__ F2, int r, int lane) {
  const int jl = (lane < 32) ? lane : 31;
  const int g7 = 130048 + (r << 5) + jl;
  int e, gI, cs0;
  if (lane < 16)      { e = 1; gI = 130560 + (r << 4) + lane;        cs0 = 2*lane; }
  else if (lane < 24) { e = 2; gI = 130816 + (r << 3) + (lane - 16); cs0 = 2*(lane-16); }
  else if (lane < 28) { e = 3; gI = 130944 + (r << 2) + (lane - 24); cs0 = 16 + 2*(lane-24); }
  else if (lane < 30) { e = 4; gI = 131008 + (r << 1) + (lane - 28); cs0 = 24 + 2*(lane-28); }
  else                { e = 5; gI = 131040 + r;                      cs0 = 28; }
  NC c7 = make_nc(nr,qsr,len,slp,twp,ssp,xsp, g7);
  NC cI = make_nc(nr,qsr,len,slp,twp,ssp,xsp, gI);
  float q07 = qp[g7];
  float q0I = qp[gI];
  float iLa = __shfl(q07, cs0), iLb = __shfl(q07, cs0 + 1);
  float iIa = __shfl(q0I, cs0), iIb = __shfl(q0I, cs0 + 1);
  const bool l1 = (e == 1);
  const float itInit = l1 ? (iLa + iLb) : (iIa + iIb);
  if (lane == 30) S2[r] = q0I;
  float qc7 = q07, qcI = q0I, ul7 = q07, ulI = q0I;
  float pu0 = 0.0f, pu1 = 0.0f;
  const float2* sb = (const float2*)S1;        // rows of 512 float2
  const int scol = (r << 5) + jl;
  unsigned* f1 = F1 + r * 42;
  spin_ge(f1, 64);                              // chunk 0 before ring init
  float2 rgs[4];
  float rg7[4], rgI4[4];
#pragma unroll
  for (int j = 0; j < 4; ++j) {
    rgs[j]  = sb[iclamp(j, 0, 336) * 512 + scol];
    rg7[j]  = qp[iclamp(j,     0, 335) * NN + g7];
    rgI4[j] = qp[iclamp(j - e, 0, 335) * NN + gI];
  }
#pragma unroll 4
  for (int s = 0; s < 344; ++s) {
    int p = s + 4;
    if (p <= 335 && (p & 7) == 0) spin_ge(f1 + (p >> 3), 64);
    float2 fo = rgs[s & 3];
    float2 fn = rgs[(s + 1) & 3];
    float gu0 = __shfl(ul7, cs0), gu1 = __shfl(ul7, cs0 + 1);
    float hu0 = __shfl(ulI, cs0), hu1 = __shfl(ulI, cs0 + 1);
    float u0 = l1 ? gu0 : hu0;
    float u1 = l1 ? gu1 : hu1;
    float it = (s == e) ? itInit : (fmaxf(pu0, Q_LBF) + fmaxf(pu1, Q_LBF));
    if (s == e) qcI = q0I;
    float qpc7 = fmaxf(rg7[s & 3],  Q_LBF);
    float qpcI = fmaxf(rgI4[s & 3], Q_LBF);
    float it7 = fmaxf(fo.x, Q_LBF) + fmaxf(fo.y, Q_LBF);
    float c17, c1i;
    float b7 = node_b(c7, qc7, qpc7, it7, c17);
    float u7n = fmaf(c17, fn.x + fn.y, b7);
    float bI = node_b(cI, qcI, qpcI, it, c1i);
    float uIn = fmaf(c1i, u0 + u1, bI);
    qc7 = fmaxf(u7n, Q_LBF); ul7 = u7n;
    qcI = fmaxf(uIn, Q_LBF); ulI = uIn;
    pu0 = u0; pu1 = u1;
    if (lane == 30 && s >= 5 && s <= 339) S2[(s - 4) * 16 + r] = uIn;
    if ((s & 7) == 3 && s >= 11 && s <= 339) {
      if (lane == 30) publish(F2 + ((s - 11) >> 3));
    }
    rgs[s & 3]  = sb[iclamp(s + 4, 0, 336) * 512 + scol];
    rg7[s & 3]  = qp[iclamp(s + 4,     0, 335) * NN + g7];
    rgI4[s & 3] = qp[iclamp(s + 4 - e, 0, 335) * NN + gI];
  }
}

// ---- role C: levels 13..16, one wave, consumes S2, writes out[0..335] ----
__device__ __forceinline__ void run_C(
    const float* __restrict__ qp,
    const float* __restrict__ nr, const float* __restrict__ qsr,
    const float* __restrict__ len, const float* __restrict__ slp,
    const float* __restrict__ twp, const float* __restrict__ ssp,
    const float* __restrict__ xsp,
    const float* __restrict__ S2, unsigned* __restrict__ F2,
    float* __restrict__ out, int lane) {
  const int jl = (lane < 8) ? lane : 7;
  const int g13 = 131056 + jl;
  int e, gI, cs0;
  if (lane < 4)      { e = 1; gI = 131064 + lane;       cs0 = 2*lane; }
  else if (lane < 6) { e = 2; gI = 131068 + (lane - 4); cs0 = 2*(lane-4); }
  else               { e = 3; gI = 131070;              cs0 = 4; }
  NC c13 = make_nc(nr,qsr,len,slp,twp,ssp,xsp, g13);
  NC cI  = make_nc(nr,qsr,len,slp,twp,ssp,xsp, gI);
  float q013 = qp[g13];
  float q0I  = qp[gI];
  float iLa = __shfl(q013, cs0), iLb = __shfl(q013, cs0 + 1);
  float iIa = __shfl(q0I,  cs0), iIb = __shfl(q0I,  cs0 + 1);
  const bool l1 = (e == 1);
  const float itInit = l1 ? (iLa + iLb) : (iIa + iIb);
  if (lane == 6) out[0] = fmaxf(q0I, Q_LBF);
  float qc13 = q013, qcI = q0I, ul13 = q013, ulI = q0I;
  float pu0 = 0.0f, pu1 = 0.0f;
  const float2* sb = (const float2*)S2;        // rows of 8 float2
  spin_ge(F2, 16);
  float2 rgs[4];
  float rg13[4], rgI4[4];
#pragma unroll
  for (int j = 0; j < 4; ++j) {
    rgs[j]  = sb[iclamp(j, 0, 336) * 8 + jl];
    rg13[j] = qp[iclamp(j,     0, 335) * NN + g13];
    rgI4[j] = qp[iclamp(j - e, 0, 335) * NN + gI];
  }
#pragma unroll 4
  for (int s = 0; s < 344; ++s) {
    int p = s + 4;
    if (p <= 335 && (p & 7) == 0) spin_ge(F2 + (p >> 3), 16);
    float2 fo = rgs[s & 3];
    float2 fn = rgs[(s + 1) & 3];
    float gu0 = __shfl(ul13, cs0), gu1 = __shfl(ul13, cs0 + 1);
    float hu0 = __shfl(ulI,  cs0), hu1 = __shfl(ulI,  cs0 + 1);
    float u0 = l1 ? gu0 : hu0;
    float u1 = l1 ? gu1 : hu1;
    float it = (s == e) ? itInit : (fmaxf(pu0, Q_LBF) + fmaxf(pu1, Q_LBF));
    if (s == e) qcI = q0I;
    float qpc13 = fmaxf(rg13[s & 3], Q_LBF);
    float qpcI  = fmaxf(rgI4[s & 3], Q_LBF);
    float it13 = fmaxf(fo.x, Q_LBF) + fmaxf(fo.y, Q_LBF);
    float c113, c1i;
    float b13 = node_b(c13, qc13, qpc13, it13, c113);
    float u13n = fmaf(c113, fn.x + fn.y, b13);
    float bI = node_b(cI, qcI, qpcI, it, c1i);
    float uIn = fmaf(c1i, u0 + u1, bI);
    qc13 = fmaxf(u13n, Q_LBF); ul13 = u13n;
    qcI  = fmaxf(uIn,  Q_LBF); ulI  = uIn;
    pu0 = u0; pu1 = u1;
    if (lane == 6 && s >= 3 && s <= 337) out[s - 2] = fmaxf(uIn, Q_LBF);
    rgs[s & 3]  = sb[iclamp(s + 4, 0, 336) * 8 + jl];
    rg13[s & 3] = qp[iclamp(s + 4,     0, 335) * NN + g13];
    rgI4[s & 3] = qp[iclamp(s + 4 - e, 0, 335) * NN + gI];
  }
}

__global__ void kinit(unsigned* __restrict__ F, int n) {
  int i = threadIdx.x;
  for (; i < n; i += 256) F[i] = 0u;
}

__global__ __launch_bounds__(320) void fused(
    const float* __restrict__ qp,
    const float* __restrict__ nr, const float* __restrict__ qsr,
    const float* __restrict__ len, const float* __restrict__ slp,
    const float* __restrict__ twp, const float* __restrict__ ssp,
    const float* __restrict__ xsp,
    float* __restrict__ S1, float* __restrict__ S2,
    unsigned* __restrict__ F1, unsigned* __restrict__ F2,
    float* __restrict__ out) {
  const int wave = threadIdx.x >> 6;
  const int lane = threadIdx.x & 63;
  if (wave < 4) {
    run_A(qp, nr, qsr, len, slp, twp, ssp, xsp, S1, F1,
          (blockIdx.x << 2) + wave, lane);
  } else if (blockIdx.x < 16) {
    run_B(qp, nr, qsr, len, slp, twp, ssp, xsp, S1, S2, F1, F2,
          blockIdx.x, lane);
  } else if (blockIdx.x == 16) {
    run_C(qp, nr, qsr, len, slp, twp, ssp, xsp, S2, F2, out, lane);
  }
}

extern "C" void kernel_launch(void* const* d_in, const int* in_sizes, int n_in,
                              void* d_out, int out_size, void* d_ws, size_t ws_size,
                              hipStream_t stream) {
  const float* q_prime = (const float*)d_in[0];
  const float* n_raw   = (const float*)d_in[1];
  const float* qs_raw  = (const float*)d_in[2];
  const float* length  = (const float*)d_in[3];
  const float* slope   = (const float*)d_in[4];
  const float* tw      = (const float*)d_in[5];
  const float* ss      = (const float*)d_in[6];
  const float* xs      = (const float*)d_in[7];
  float* out = (float*)d_out;
  float* S1 = (float*)d_ws;                    // 337 x 1024 level-6 series
  float* S2 = S1 + 337 * 1024;                 // 337 x 16 level-12 series
  unsigned* F1 = (unsigned*)(S2 + 337 * 16);   // 16 consumers x 42 chunk counters
  unsigned* F2 = F1 + 16 * 42;                 // 42 chunk counters
  kinit<<<1, 256, 0, stream>>>(F1, 16 * 42 + 42);
  fused<<<256, 320, 0, stream>>>(q_prime, n_raw, qs_raw, length, slope, tw, ss, xs,
                                 S1, S2, F1, F2, out);
}

// Round 5
// 464.019 us; speedup vs baseline: 3.7717x; 3.7717x over previous
//
#include <hip/hip_runtime.h>

#define Q_LBF 1e-4f
#define DTF   3600.0f
#define NN    131071
#define SENT  0x7FC00001u   // NaN sentinel: computed stream values are always finite

#if __has_builtin(__builtin_amdgcn_exp2f)
#define FEXP2(x) __builtin_amdgcn_exp2f(x)
#else
#define FEXP2(x) exp2f(x)
#endif
#if __has_builtin(__builtin_amdgcn_logf)
#define FLOG2(x) __builtin_amdgcn_logf(x)
#else
#define FLOG2(x) log2f(x)
#endif
#if __has_builtin(__builtin_amdgcn_rcpf)
#define FRCP(x) __builtin_amdgcn_rcpf(x)
#else
#define FRCP(x) (1.0f/(x))
#endif

// Per-node time-invariant constants (everything except q folded once).
struct NC { float a1, e, tw, ssd, w2, a2, kd, kx; };

__device__ __forceinline__ NC make_nc(const float* __restrict__ nr,
                                      const float* __restrict__ qsr,
                                      const float* __restrict__ len,
                                      const float* __restrict__ slp,
                                      const float* __restrict__ twp,
                                      const float* __restrict__ ssp,
                                      const float* __restrict__ xsp,
                                      int g) {
  float n  = fmaf(nr[g], 0.34f, 0.01f);
  float qs = 3.0f * qsr[g];
  float s0 = fmaxf(slp[g], 1e-4f);
  float rs = sqrtf(s0);
  float L  = len[g];
  float x  = xsp[g];
  float ss = ssp[g];
  NC c;
  c.a1  = n * (qs + 1.0f) / fmaf(21.0f, rs, 1e-8f);
  c.e   = 3.0f / fmaf(3.0f, qs, 5.0f);
  c.tw  = twp[g];
  c.ssd = 2.0f * ss;
  c.w2  = 2.0f * sqrtf(fmaf(ss, ss, 1.0f));
  c.a2  = rs / n;
  float kl = 1.2f * L;
  c.kd  = kl * (1.0f - x);
  c.kx  = kl * x;
  return c;
}

__device__ __forceinline__ float node_b(const NC& c, float q, float qpc, float it,
                                        float& c1o) {
  float z    = q * c.a1;
  float d    = fmaxf(FEXP2(c.e * FLOG2(z)), 0.01f);
  float bot  = fmaxf(fmaf(-c.ssd, d, c.tw), 0.1f);
  float area = (c.tw + bot) * (0.5f * d);
  float wet  = fmaf(c.w2, d, bot);
  float R    = area * FRCP(wet);
  float v2   = c.a2 * FEXP2(0.66666668f * FLOG2(R));
  v2 = fminf(fmaxf(v2, 0.3f), 15.0f);
  float rv   = FRCP(v2);
  float rden = FRCP(fmaf(c.kd, rv, DTF));
  float c2   = fmaf(c.kx, rv, DTF) * rden;
  float c4   = 7200.0f * rden;
  c1o = c4 - c2;
  float c3 = 1.0f - c4;
  return fmaf(c2, it, fmaf(c3, q, c4 * qpc));
}

__device__ __forceinline__ int iclamp(int v, int lo, int hi) {
  return v < lo ? lo : (v > hi ? hi : v);
}

// Fence-free cross-XCD streaming: relaxed agent-scope atomics (sc1 — bypass
// non-coherent L1/per-XCD-L2, operate at the LLC coherence point). One writer
// per word; 32-bit words can't tear; sentinel = "not yet written".
__device__ __forceinline__ void st_stream(float* p, float v) {
  __hip_atomic_store((unsigned*)p, __float_as_uint(v),
                     __ATOMIC_RELAXED, __HIP_MEMORY_SCOPE_AGENT);
}
__device__ __forceinline__ float2 poll2(const float* p) {
  const unsigned* u = (const unsigned*)p;
  unsigned a = __hip_atomic_load(u,     __ATOMIC_RELAXED, __HIP_MEMORY_SCOPE_AGENT);
  unsigned b = __hip_atomic_load(u + 1, __ATOMIC_RELAXED, __HIP_MEMORY_SCOPE_AGENT);
  while (a == SENT) {
    __builtin_amdgcn_s_sleep(1);
    a = __hip_atomic_load(u, __ATOMIC_RELAXED, __HIP_MEMORY_SCOPE_AGENT);
  }
  while (b == SENT) {
    __builtin_amdgcn_s_sleep(1);
    b = __hip_atomic_load(u + 1, __ATOMIC_RELAXED, __HIP_MEMORY_SCOPE_AGENT);
  }
  return make_float2(__uint_as_float(a), __uint_as_float(b));
}

// ---- role A: levels 0..6, one depth-7 subtree per wave (1024 waves) ----
__device__ __forceinline__ void run_A(
    const float* __restrict__ qp,
    const float* __restrict__ nr, const float* __restrict__ qsr,
    const float* __restrict__ len, const float* __restrict__ slp,
    const float* __restrict__ twp, const float* __restrict__ ssp,
    const float* __restrict__ xsp,
    float* __restrict__ S1, int wv, int lane) {
  const int g_leaf = (wv << 6) + lane;
  int e, g_int, cs0;
  if (lane < 32)      { e = 1; g_int = 65536  + (wv << 5) + lane;        cs0 = 2*lane; }
  else if (lane < 48) { e = 2; g_int = 98304  + (wv << 4) + (lane - 32); cs0 = 2*(lane-32); }
  else if (lane < 56) { e = 3; g_int = 114688 + (wv << 3) + (lane - 48); cs0 = 32 + 2*(lane-48); }
  else if (lane < 60) { e = 4; g_int = 122880 + (wv << 2) + (lane - 56); cs0 = 48 + 2*(lane-56); }
  else if (lane < 62) { e = 5; g_int = 126976 + (wv << 1) + (lane - 60); cs0 = 56 + 2*(lane-60); }
  else                { e = 6; g_int = 129024 + wv;                      cs0 = 60; }
  NC cL = make_nc(nr,qsr,len,slp,twp,ssp,xsp, g_leaf);
  NC cI = make_nc(nr,qsr,len,slp,twp,ssp,xsp, g_int);
  float q0L = qp[g_leaf];
  float q0I = qp[g_int];
  float iLa = __shfl(q0L, cs0), iLb = __shfl(q0L, cs0 + 1);
  float iIa = __shfl(q0I, cs0), iIb = __shfl(q0I, cs0 + 1);
  const bool l1 = (e == 1);
  const float itInit = l1 ? (iLa + iLb) : (iIa + iIb);   // raw children q0 (t=0 i_t)
  if (lane == 62) st_stream(&S1[wv], q0I);
  float qcL = q0L, qcI = q0I, ulL = q0L, ulI = q0I;
  float pu0 = 0.0f, pu1 = 0.0f;
  float rgL[4], rgI[4];
#pragma unroll
  for (int j = 0; j < 4; ++j) {
    rgL[j] = qp[iclamp(j,     0, 335) * NN + g_leaf];
    rgI[j] = qp[iclamp(j - e, 0, 335) * NN + g_int];
  }
#pragma unroll 4
  for (int s = 0; s < 344; ++s) {
    float guL0 = __shfl(ulL, cs0), guL1 = __shfl(ulL, cs0 + 1);
    float guI0 = __shfl(ulI, cs0), guI1 = __shfl(ulI, cs0 + 1);
    float u0 = l1 ? guL0 : guI0;
    float u1 = l1 ? guL1 : guI1;
    // children state at t = clamp(u gathered LAST iter); t=0 case precomputed
    float it = (s == e) ? itInit : (fmaxf(pu0, Q_LBF) + fmaxf(pu1, Q_LBF));
    if (s == e) qcI = q0I;                     // epoch start: raw q_prime[0]
    float qpcL = fmaxf(rgL[s & 3], Q_LBF);
    float qpcI = fmaxf(rgI[s & 3], Q_LBF);
    float c1l, c1i;
    float bL = node_b(cL, qcL, qpcL, 0.0f, c1l);
    float bI = node_b(cI, qcI, qpcI, it,   c1i);
    float uIn = fmaf(c1i, u0 + u1, bI);        // shuffle result consumed LAST
    qcL = fmaxf(bL,  Q_LBF); ulL = bL;
    qcI = fmaxf(uIn, Q_LBF); ulI = uIn;
    pu0 = u0; pu1 = u1;
    if (lane == 62 && s >= 6 && s <= 340) st_stream(&S1[(s - 5) * 1024 + wv], uIn);
    rgL[s & 3] = qp[iclamp(s + 4,     0, 335) * NN + g_leaf];
    rgI[s & 3] = qp[iclamp(s + 4 - e, 0, 335) * NN + g_int];
  }
}

// ---- role B: levels 7..12, 16 waves, consumes S1 stream, produces S2 ----
__device__ __forceinline__ void run_B(
    const float* __restrict__ qp,
    const float* __restrict__ nr, const float* __restrict__ qsr,
    const float* __restrict__ len, const float* __restrict__ slp,
    const float* __restrict__ twp, const float* __restrict__ ssp,
    const float* __restrict__ xsp,
    const float* __restrict__ S1, float* __restrict__ S2, int r, int lane) {
  const int jl = (lane < 32) ? lane : 31;
  const int g7 = 130048 + (r << 5) + jl;
  int e, gI, cs0;
  if (lane < 16)      { e = 1; gI = 130560 + (r << 4) + lane;        cs0 = 2*lane; }
  else if (lane < 24) { e = 2; gI = 130816 + (r << 3) + (lane - 16); cs0 = 2*(lane-16); }
  else if (lane < 28) { e = 3; gI = 130944 + (r << 2) + (lane - 24); cs0 = 16 + 2*(lane-24); }
  else if (lane < 30) { e = 4; gI = 131008 + (r << 1) + (lane - 28); cs0 = 24 + 2*(lane-28); }
  else                { e = 5; gI = 131040 + r;                      cs0 = 28; }
  NC c7 = make_nc(nr,qsr,len,slp,twp,ssp,xsp, g7);
  NC cI = make_nc(nr,qsr,len,slp,twp,ssp,xsp, gI);
  float q07 = qp[g7];
  float q0I = qp[gI];
  float iLa = __shfl(q07, cs0), iLb = __shfl(q07, cs0 + 1);
  float iIa = __shfl(q0I, cs0), iIb = __shfl(q0I, cs0 + 1);
  const bool l1 = (e == 1);
  const float itInit = l1 ? (iLa + iLb) : (iIa + iIb);
  if (lane == 30) st_stream(&S2[r], q0I);
  float qc7 = q07, qcI = q0I, ul7 = q07, ulI = q0I;
  float pu0 = 0.0f, pu1 = 0.0f;
  const int col2 = ((r << 5) + jl) * 2;        // child pair columns in S1 rows of 1024
  float2 rgs[4];
  float rg7[4], rgI4[4];
#pragma unroll
  for (int j = 0; j < 4; ++j) {
    rgs[j]  = poll2(S1 + iclamp(j, 0, 335) * 1024 + col2);
    rg7[j]  = qp[iclamp(j,     0, 335) * NN + g7];
    rgI4[j] = qp[iclamp(j - e, 0, 335) * NN + gI];
  }
#pragma unroll 4
  for (int s = 0; s < 344; ++s) {
    float2 fo = rgs[s & 3];                    // row s   (old children state, clamp)
    float2 fn = rgs[(s + 1) & 3];              // row s+1 (raw new children sweep)
    float gu0 = __shfl(ul7, cs0), gu1 = __shfl(ul7, cs0 + 1);
    float hu0 = __shfl(ulI, cs0), hu1 = __shfl(ulI, cs0 + 1);
    float u0 = l1 ? gu0 : hu0;
    float u1 = l1 ? gu1 : hu1;
    float it = (s == e) ? itInit : (fmaxf(pu0, Q_LBF) + fmaxf(pu1, Q_LBF));
    if (s == e) qcI = q0I;
    float qpc7 = fmaxf(rg7[s & 3],  Q_LBF);
    float qpcI = fmaxf(rgI4[s & 3], Q_LBF);
    float it7 = fmaxf(fo.x, Q_LBF) + fmaxf(fo.y, Q_LBF);
    float c17, c1i;
    float b7 = node_b(c7, qc7, qpc7, it7, c17);
    float u7n = fmaf(c17, fn.x + fn.y, b7);
    float bI = node_b(cI, qcI, qpcI, it, c1i);
    float uIn = fmaf(c1i, u0 + u1, bI);
    qc7 = fmaxf(u7n, Q_LBF); ul7 = u7n;
    qcI = fmaxf(uIn, Q_LBF); ulI = uIn;
    pu0 = u0; pu1 = u1;
    if (lane == 30 && s >= 5 && s <= 339) st_stream(&S2[(s - 4) * 16 + r], uIn);
    rgs[s & 3]  = poll2(S1 + iclamp(s + 4, 0, 335) * 1024 + col2);  // row 336 never produced
    rg7[s & 3]  = qp[iclamp(s + 4,     0, 335) * NN + g7];
    rgI4[s & 3] = qp[iclamp(s + 4 - e, 0, 335) * NN + gI];
  }
}

// ---- role C: levels 13..16, one wave, consumes S2, writes out[0..335] ----
__device__ __forceinline__ void run_C(
    const float* __restrict__ qp,
    const float* __restrict__ nr, const float* __restrict__ qsr,
    const float* __restrict__ len, const float* __restrict__ slp,
    const float* __restrict__ twp, const float* __restrict__ ssp,
    const float* __restrict__ xsp,
    const float* __restrict__ S2, float* __restrict__ out, int lane) {
  const int jl = (lane < 8) ? lane : 7;
  const int g13 = 131056 + jl;
  int e, gI, cs0;
  if (lane < 4)      { e = 1; gI = 131064 + lane;       cs0 = 2*lane; }
  else if (lane < 6) { e = 2; gI = 131068 + (lane - 4); cs0 = 2*(lane-4); }
  else               { e = 3; gI = 131070;              cs0 = 4; }
  NC c13 = make_nc(nr,qsr,len,slp,twp,ssp,xsp, g13);
  NC cI  = make_nc(nr,qsr,len,slp,twp,ssp,xsp, gI);
  float q013 = qp[g13];
  float q0I  = qp[gI];
  float iLa = __shfl(q013, cs0), iLb = __shfl(q013, cs0 + 1);
  float iIa = __shfl(q0I,  cs0), iIb = __shfl(q0I,  cs0 + 1);
  const bool l1 = (e == 1);
  const float itInit = l1 ? (iLa + iLb) : (iIa + iIb);
  if (lane == 6) out[0] = fmaxf(q0I, Q_LBF);
  float qc13 = q013, qcI = q0I, ul13 = q013, ulI = q0I;
  float pu0 = 0.0f, pu1 = 0.0f;
  const int col2 = jl * 2;                     // child pair columns in S2 rows of 16
  float2 rgs[4];
  float rg13[4], rgI4[4];
#pragma unroll
  for (int j = 0; j < 4; ++j) {
    rgs[j]  = poll2(S2 + iclamp(j, 0, 335) * 16 + col2);
    rg13[j] = qp[iclamp(j,     0, 335) * NN + g13];
    rgI4[j] = qp[iclamp(j - e, 0, 335) * NN + gI];
  }
#pragma unroll 4
  for (int s = 0; s < 344; ++s) {
    float2 fo = rgs[s & 3];
    float2 fn = rgs[(s + 1) & 3];
    float gu0 = __shfl(ul13, cs0), gu1 = __shfl(ul13, cs0 + 1);
    float hu0 = __shfl(ulI,  cs0), hu1 = __shfl(ulI,  cs0 + 1);
    float u0 = l1 ? gu0 : hu0;
    float u1 = l1 ? gu1 : hu1;
    float it = (s == e) ? itInit : (fmaxf(pu0, Q_LBF) + fmaxf(pu1, Q_LBF));
    if (s == e) qcI = q0I;
    float qpc13 = fmaxf(rg13[s & 3], Q_LBF);
    float qpcI  = fmaxf(rgI4[s & 3], Q_LBF);
    float it13 = fmaxf(fo.x, Q_LBF) + fmaxf(fo.y, Q_LBF);
    float c113, c1i;
    float b13 = node_b(c13, qc13, qpc13, it13, c113);
    float u13n = fmaf(c113, fn.x + fn.y, b13);
    float bI = node_b(cI, qcI, qpcI, it, c1i);
    float uIn = fmaf(c1i, u0 + u1, bI);
    qc13 = fmaxf(u13n, Q_LBF); ul13 = u13n;
    qcI  = fmaxf(uIn,  Q_LBF); ulI  = uIn;
    pu0 = u0; pu1 = u1;
    if (lane == 6 && s >= 3 && s <= 337) out[s - 2] = fmaxf(uIn, Q_LBF);
    rgs[s & 3]  = poll2(S2 + iclamp(s + 4, 0, 335) * 16 + col2);
    rg13[s & 3] = qp[iclamp(s + 4,     0, 335) * NN + g13];
    rgI4[s & 3] = qp[iclamp(s + 4 - e, 0, 335) * NN + gI];
  }
}

__global__ __launch_bounds__(256) void kinit(unsigned* __restrict__ F, int n) {
  int i = blockIdx.x * 256 + threadIdx.x;
  int stride = gridDim.x * 256;
  for (; i < n; i += stride) F[i] = SENT;
}

__global__ __launch_bounds__(320) void fused(
    const float* __restrict__ qp,
    const float* __restrict__ nr, const float* __restrict__ qsr,
    const float* __restrict__ len, const float* __restrict__ slp,
    const float* __restrict__ twp, const float* __restrict__ ssp,
    const float* __restrict__ xsp,
    float* __restrict__ S1, float* __restrict__ S2,
    float* __restrict__ out) {
  const int wave = threadIdx.x >> 6;
  const int lane = threadIdx.x & 63;
  if (wave < 4) {
    run_A(qp, nr, qsr, len, slp, twp, ssp, xsp, S1,
          (blockIdx.x << 2) + wave, lane);
  } else if (blockIdx.x < 16) {
    run_B(qp, nr, qsr, len, slp, twp, ssp, xsp, S1, S2, blockIdx.x, lane);
  } else if (blockIdx.x == 16) {
    run_C(qp, nr, qsr, len, slp, twp, ssp, xsp, S2, out, lane);
  }
}

extern "C" void kernel_launch(void* const* d_in, const int* in_sizes, int n_in,
                              void* d_out, int out_size, void* d_ws, size_t ws_size,
                              hipStream_t stream) {
  const float* q_prime = (const float*)d_in[0];
  const float* n_raw   = (const float*)d_in[1];
  const float* qs_raw  = (const float*)d_in[2];
  const float* length  = (const float*)d_in[3];
  const float* slope   = (const float*)d_in[4];
  const float* tw      = (const float*)d_in[5];
  const float* ss      = (const float*)d_in[6];
  const float* xs      = (const float*)d_in[7];
  float* out = (float*)d_out;
  float* S1 = (float*)d_ws;                    // 337 x 1024 level-6 series (sentinel-init)
  float* S2 = S1 + 337 * 1024;                 // 337 x 16 level-12 series (sentinel-init)
  const int nsent = 337 * 1024 + 337 * 16;
  kinit<<<128, 256, 0, stream>>>((unsigned*)d_ws, nsent);
  fused<<<256, 320, 0, stream>>>(q_prime, n_raw, qs_raw, length, slope, tw, ss, xs,
                                 S1, S2, out);
}

// Round 6
// 369.871 us; speedup vs baseline: 4.7317x; 1.2545x over previous
//
#include <hip/hip_runtime.h>

#define Q_LBF 1e-4f
#define DTF   3600.0f
#define NN    131071
#define SENT  0x7FC00001u   // NaN sentinel: computed stream values are always finite

#if __has_builtin(__builtin_amdgcn_exp2f)
#define FEXP2(x) __builtin_amdgcn_exp2f(x)
#else
#define FEXP2(x) exp2f(x)
#endif
#if __has_builtin(__builtin_amdgcn_logf)
#define FLOG2(x) __builtin_amdgcn_logf(x)
#else
#define FLOG2(x) log2f(x)
#endif
#if __has_builtin(__builtin_amdgcn_rcpf)
#define FRCP(x) __builtin_amdgcn_rcpf(x)
#else
#define FRCP(x) (1.0f/(x))
#endif

// Per-node time-invariant constants (everything except q folded once).
struct NC { float a1, e, tw, ssd, w2, a2, kd, kx; };

__device__ __forceinline__ NC make_nc(const float* __restrict__ nr,
                                      const float* __restrict__ qsr,
                                      const float* __restrict__ len,
                                      const float* __restrict__ slp,
                                      const float* __restrict__ twp,
                                      const float* __restrict__ ssp,
                                      const float* __restrict__ xsp,
                                      int g) {
  float n  = fmaf(nr[g], 0.34f, 0.01f);
  float qs = 3.0f * qsr[g];
  float s0 = fmaxf(slp[g], 1e-4f);
  float rs = sqrtf(s0);
  float L  = len[g];
  float x  = xsp[g];
  float ss = ssp[g];
  NC c;
  c.a1  = n * (qs + 1.0f) / fmaf(21.0f, rs, 1e-8f);
  c.e   = 3.0f / fmaf(3.0f, qs, 5.0f);
  c.tw  = twp[g];
  c.ssd = 2.0f * ss;
  c.w2  = 2.0f * sqrtf(fmaf(ss, ss, 1.0f));
  c.a2  = rs / n;
  float kl = 1.2f * L;
  c.kd  = kl * (1.0f - x);
  c.kx  = kl * x;
  return c;
}

__device__ __forceinline__ float node_b(const NC& c, float q, float qpc, float it,
                                        float& c1o) {
  float z    = q * c.a1;
  float d    = fmaxf(FEXP2(c.e * FLOG2(z)), 0.01f);
  float bot  = fmaxf(fmaf(-c.ssd, d, c.tw), 0.1f);
  float area = (c.tw + bot) * (0.5f * d);
  float wet  = fmaf(c.w2, d, bot);
  float R    = area * FRCP(wet);
  float v2   = c.a2 * FEXP2(0.66666668f * FLOG2(R));
  v2 = fminf(fmaxf(v2, 0.3f), 15.0f);
  float rv   = FRCP(v2);
  float rden = FRCP(fmaf(c.kd, rv, DTF));
  float c2   = fmaf(c.kx, rv, DTF) * rden;
  float c4   = 7200.0f * rden;
  c1o = c4 - c2;
  float c3 = 1.0f - c4;
  return fmaf(c2, it, fmaf(c3, q, c4 * qpc));
}

__device__ __forceinline__ int iclamp(int v, int lo, int hi) {
  return v < lo ? lo : (v > hi ? hi : v);
}

// Fence-free cross-XCD streaming via relaxed agent-scope atomics (sc1 —
// bypass non-coherent L1/per-XCD-L2, operate at the LLC coherence point).
// One writer per word; 32-bit words can't tear; sentinel = "not written yet".
__device__ __forceinline__ void st_stream(float* p, float v) {
  __hip_atomic_store((unsigned*)p, __float_as_uint(v),
                     __ATOMIC_RELAXED, __HIP_MEMORY_SCOPE_AGENT);
}
// Non-blocking pair read: NO sentinel check at issue (check deferred to use).
__device__ __forceinline__ uint2 ld2_relaxed(const float* p) {
  const unsigned* u = (const unsigned*)p;
  uint2 r;
  r.x = __hip_atomic_load(u,     __ATOMIC_RELAXED, __HIP_MEMORY_SCOPE_AGENT);
  r.y = __hip_atomic_load(u + 1, __ATOMIC_RELAXED, __HIP_MEMORY_SCOPE_AGENT);
  return r;
}
// Blocking pair read: rare slow path when deferred check finds the sentinel.
__device__ __forceinline__ uint2 ld2_block(const float* p) {
  uint2 r = ld2_relaxed(p);
  while (r.x == SENT || r.y == SENT) {
    __builtin_amdgcn_s_sleep(1);
    r = ld2_relaxed(p);
  }
  return r;
}

// ---- role A: levels 0..6, one depth-7 subtree per wave (1024 waves) ----
__device__ __forceinline__ void run_A(
    const float* __restrict__ qp,
    const float* __restrict__ nr, const float* __restrict__ qsr,
    const float* __restrict__ len, const float* __restrict__ slp,
    const float* __restrict__ twp, const float* __restrict__ ssp,
    const float* __restrict__ xsp,
    float* __restrict__ S1, int wv, int lane) {
  const int g_leaf = (wv << 6) + lane;
  int e, g_int, cs0;
  if (lane < 32)      { e = 1; g_int = 65536  + (wv << 5) + lane;        cs0 = 2*lane; }
  else if (lane < 48) { e = 2; g_int = 98304  + (wv << 4) + (lane - 32); cs0 = 2*(lane-32); }
  else if (lane < 56) { e = 3; g_int = 114688 + (wv << 3) + (lane - 48); cs0 = 32 + 2*(lane-48); }
  else if (lane < 60) { e = 4; g_int = 122880 + (wv << 2) + (lane - 56); cs0 = 48 + 2*(lane-56); }
  else if (lane < 62) { e = 5; g_int = 126976 + (wv << 1) + (lane - 60); cs0 = 56 + 2*(lane-60); }
  else                { e = 6; g_int = 129024 + wv;                      cs0 = 60; }
  NC cL = make_nc(nr,qsr,len,slp,twp,ssp,xsp, g_leaf);
  NC cI = make_nc(nr,qsr,len,slp,twp,ssp,xsp, g_int);
  float q0L = qp[g_leaf];
  float q0I = qp[g_int];
  float iLa = __shfl(q0L, cs0), iLb = __shfl(q0L, cs0 + 1);
  float iIa = __shfl(q0I, cs0), iIb = __shfl(q0I, cs0 + 1);
  const bool l1 = (e == 1);
  const float itInit = l1 ? (iLa + iLb) : (iIa + iIb);   // raw children q0 (t=0 i_t)
  if (lane == 62) st_stream(&S1[wv], q0I);
  float qcL = q0L, qcI = q0I, ulL = q0L, ulI = q0I;
  float pu0 = 0.0f, pu1 = 0.0f;
  float rgL[4], rgI[4];
#pragma unroll
  for (int j = 0; j < 4; ++j) {
    rgL[j] = qp[iclamp(j,     0, 335) * NN + g_leaf];
    rgI[j] = qp[iclamp(j - e, 0, 335) * NN + g_int];
  }
#pragma unroll 4
  for (int s = 0; s < 344; ++s) {
    float guL0 = __shfl(ulL, cs0), guL1 = __shfl(ulL, cs0 + 1);
    float guI0 = __shfl(ulI, cs0), guI1 = __shfl(ulI, cs0 + 1);
    float u0 = l1 ? guL0 : guI0;
    float u1 = l1 ? guL1 : guI1;
    // children state at t = clamp(u gathered LAST iter); t=0 case precomputed
    float it = (s == e) ? itInit : (fmaxf(pu0, Q_LBF) + fmaxf(pu1, Q_LBF));
    if (s == e) qcI = q0I;                     // epoch start: raw q_prime[0]
    float qpcL = fmaxf(rgL[s & 3], Q_LBF);
    float qpcI = fmaxf(rgI[s & 3], Q_LBF);
    float c1l, c1i;
    float bL = node_b(cL, qcL, qpcL, 0.0f, c1l);
    float bI = node_b(cI, qcI, qpcI, it,   c1i);
    float uIn = fmaf(c1i, u0 + u1, bI);        // shuffle result consumed LAST
    qcL = fmaxf(bL,  Q_LBF); ulL = bL;
    qcI = fmaxf(uIn, Q_LBF); ulI = uIn;
    pu0 = u0; pu1 = u1;
    if (lane == 62 && s >= 6 && s <= 340) st_stream(&S1[(s - 5) * 1024 + wv], uIn);
    rgL[s & 3] = qp[iclamp(s + 4,     0, 335) * NN + g_leaf];
    rgI[s & 3] = qp[iclamp(s + 4 - e, 0, 335) * NN + g_int];
  }
}

// ---- role B: levels 7..12, 16 waves, consumes S1 stream, produces S2 ----
__device__ __forceinline__ void run_B(
    const float* __restrict__ qp,
    const float* __restrict__ nr, const float* __restrict__ qsr,
    const float* __restrict__ len, const float* __restrict__ slp,
    const float* __restrict__ twp, const float* __restrict__ ssp,
    const float* __restrict__ xsp,
    const float* __restrict__ S1, float* __restrict__ S2, int r, int lane) {
  const int jl = (lane < 32) ? lane : 31;
  const int g7 = 130048 + (r << 5) + jl;
  int e, gI, cs0;
  if (lane < 16)      { e = 1; gI = 130560 + (r << 4) + lane;        cs0 = 2*lane; }
  else if (lane < 24) { e = 2; gI = 130816 + (r << 3) + (lane - 16); cs0 = 2*(lane-16); }
  else if (lane < 28) { e = 3; gI = 130944 + (r << 2) + (lane - 24); cs0 = 16 + 2*(lane-24); }
  else if (lane < 30) { e = 4; gI = 131008 + (r << 1) + (lane - 28); cs0 = 24 + 2*(lane-28); }
  else                { e = 5; gI = 131040 + r;                      cs0 = 28; }
  NC c7 = make_nc(nr,qsr,len,slp,twp,ssp,xsp, g7);
  NC cI = make_nc(nr,qsr,len,slp,twp,ssp,xsp, gI);
  float q07 = qp[g7];
  float q0I = qp[gI];
  float iLa = __shfl(q07, cs0), iLb = __shfl(q07, cs0 + 1);
  float iIa = __shfl(q0I, cs0), iIb = __shfl(q0I, cs0 + 1);
  const bool l1 = (e == 1);
  const float itInit = l1 ? (iLa + iLb) : (iIa + iIb);
  if (lane == 30) st_stream(&S2[r], q0I);
  float qc7 = q07, qcI = q0I, ul7 = q07, ulI = q0I;
  float pu0 = 0.0f, pu1 = 0.0f;
  const int col2 = ((r << 5) + jl) * 2;        // child pair columns in S1 rows of 1024
  uint2 rgs[8];                                // distance-8 NON-BLOCKING stream ring
  float rg7[4], rgI4[4];
#pragma unroll
  for (int j = 0; j < 8; ++j) rgs[j] = ld2_relaxed(S1 + iclamp(j, 0, 335) * 1024 + col2);
#pragma unroll
  for (int j = 0; j < 4; ++j) {
    rg7[j]  = qp[iclamp(j,     0, 335) * NN + g7];
    rgI4[j] = qp[iclamp(j - e, 0, 335) * NN + gI];
  }
#pragma unroll 8
  for (int s = 0; s < 344; ++s) {
    uint2 fo = rgs[s & 7];                     // row s   (old children state)
    uint2 fn = rgs[(s + 1) & 7];               // row s+1 (raw new children sweep)
    // deferred sentinel check — common path: 4 compares, branch not taken
    if (__builtin_expect((fo.x == SENT) | (fo.y == SENT) |
                         (fn.x == SENT) | (fn.y == SENT), 0)) {
      fo = ld2_block(S1 + iclamp(s,     0, 335) * 1024 + col2);
      fn = ld2_block(S1 + iclamp(s + 1, 0, 335) * 1024 + col2);
      rgs[(s + 1) & 7] = fn;                   // fn becomes next iter's fo
    }
    float fox = __uint_as_float(fo.x), foy = __uint_as_float(fo.y);
    float fnx = __uint_as_float(fn.x), fny = __uint_as_float(fn.y);
    float gu0 = __shfl(ul7, cs0), gu1 = __shfl(ul7, cs0 + 1);
    float hu0 = __shfl(ulI, cs0), hu1 = __shfl(ulI, cs0 + 1);
    float u0 = l1 ? gu0 : hu0;
    float u1 = l1 ? gu1 : hu1;
    float it = (s == e) ? itInit : (fmaxf(pu0, Q_LBF) + fmaxf(pu1, Q_LBF));
    if (s == e) qcI = q0I;
    float qpc7 = fmaxf(rg7[s & 3],  Q_LBF);
    float qpcI = fmaxf(rgI4[s & 3], Q_LBF);
    float it7 = fmaxf(fox, Q_LBF) + fmaxf(foy, Q_LBF);
    float c17, c1i;
    float b7 = node_b(c7, qc7, qpc7, it7, c17);
    float u7n = fmaf(c17, fnx + fny, b7);
    float bI = node_b(cI, qcI, qpcI, it, c1i);
    float uIn = fmaf(c1i, u0 + u1, bI);
    qc7 = fmaxf(u7n, Q_LBF); ul7 = u7n;
    qcI = fmaxf(uIn, Q_LBF); ulI = uIn;
    pu0 = u0; pu1 = u1;
    if (lane == 30 && s >= 5 && s <= 339) st_stream(&S2[(s - 4) * 16 + r], uIn);
    rgs[s & 7] = ld2_relaxed(S1 + iclamp(s + 8, 0, 335) * 1024 + col2);
    rg7[s & 3]  = qp[iclamp(s + 4,     0, 335) * NN + g7];
    rgI4[s & 3] = qp[iclamp(s + 4 - e, 0, 335) * NN + gI];
  }
}

// ---- role C: levels 13..16, one wave, consumes S2, writes out[0..335] ----
__device__ __forceinline__ void run_C(
    const float* __restrict__ qp,
    const float* __restrict__ nr, const float* __restrict__ qsr,
    const float* __restrict__ len, const float* __restrict__ slp,
    const float* __restrict__ twp, const float* __restrict__ ssp,
    const float* __restrict__ xsp,
    const float* __restrict__ S2, float* __restrict__ out, int lane) {
  const int jl = (lane < 8) ? lane : 7;
  const int g13 = 131056 + jl;
  int e, gI, cs0;
  if (lane < 4)      { e = 1; gI = 131064 + lane;       cs0 = 2*lane; }
  else if (lane < 6) { e = 2; gI = 131068 + (lane - 4); cs0 = 2*(lane-4); }
  else               { e = 3; gI = 131070;              cs0 = 4; }
  NC c13 = make_nc(nr,qsr,len,slp,twp,ssp,xsp, g13);
  NC cI  = make_nc(nr,qsr,len,slp,twp,ssp,xsp, gI);
  float q013 = qp[g13];
  float q0I  = qp[gI];
  float iLa = __shfl(q013, cs0), iLb = __shfl(q013, cs0 + 1);
  float iIa = __shfl(q0I,  cs0), iIb = __shfl(q0I,  cs0 + 1);
  const bool l1 = (e == 1);
  const float itInit = l1 ? (iLa + iLb) : (iIa + iIb);
  if (lane == 6) out[0] = fmaxf(q0I, Q_LBF);
  float qc13 = q013, qcI = q0I, ul13 = q013, ulI = q0I;
  float pu0 = 0.0f, pu1 = 0.0f;
  const int col2 = jl * 2;                     // child pair columns in S2 rows of 16
  uint2 rgs[8];
  float rg13[4], rgI4[4];
#pragma unroll
  for (int j = 0; j < 8; ++j) rgs[j] = ld2_relaxed(S2 + iclamp(j, 0, 335) * 16 + col2);
#pragma unroll
  for (int j = 0; j < 4; ++j) {
    rg13[j] = qp[iclamp(j,     0, 335) * NN + g13];
    rgI4[j] = qp[iclamp(j - e, 0, 335) * NN + gI];
  }
#pragma unroll 8
  for (int s = 0; s < 344; ++s) {
    uint2 fo = rgs[s & 7];
    uint2 fn = rgs[(s + 1) & 7];
    if (__builtin_expect((fo.x == SENT) | (fo.y == SENT) |
                         (fn.x == SENT) | (fn.y == SENT), 0)) {
      fo = ld2_block(S2 + iclamp(s,     0, 335) * 16 + col2);
      fn = ld2_block(S2 + iclamp(s + 1, 0, 335) * 16 + col2);
      rgs[(s + 1) & 7] = fn;
    }
    float fox = __uint_as_float(fo.x), foy = __uint_as_float(fo.y);
    float fnx = __uint_as_float(fn.x), fny = __uint_as_float(fn.y);
    float gu0 = __shfl(ul13, cs0), gu1 = __shfl(ul13, cs0 + 1);
    float hu0 = __shfl(ulI,  cs0), hu1 = __shfl(ulI,  cs0 + 1);
    float u0 = l1 ? gu0 : hu0;
    float u1 = l1 ? gu1 : hu1;
    float it = (s == e) ? itInit : (fmaxf(pu0, Q_LBF) + fmaxf(pu1, Q_LBF));
    if (s == e) qcI = q0I;
    float qpc13 = fmaxf(rg13[s & 3], Q_LBF);
    float qpcI  = fmaxf(rgI4[s & 3], Q_LBF);
    float it13 = fmaxf(fox, Q_LBF) + fmaxf(foy, Q_LBF);
    float c113, c1i;
    float b13 = node_b(c13, qc13, qpc13, it13, c113);
    float u13n = fmaf(c113, fnx + fny, b13);
    float bI = node_b(cI, qcI, qpcI, it, c1i);
    float uIn = fmaf(c1i, u0 + u1, bI);
    qc13 = fmaxf(u13n, Q_LBF); ul13 = u13n;
    qcI  = fmaxf(uIn,  Q_LBF); ulI  = uIn;
    pu0 = u0; pu1 = u1;
    if (lane == 6 && s >= 3 && s <= 337) out[s - 2] = fmaxf(uIn, Q_LBF);
    rgs[s & 7] = ld2_relaxed(S2 + iclamp(s + 8, 0, 335) * 16 + col2);
    rg13[s & 3] = qp[iclamp(s + 4,     0, 335) * NN + g13];
    rgI4[s & 3] = qp[iclamp(s + 4 - e, 0, 335) * NN + gI];
  }
}

__global__ __launch_bounds__(256) void kinit(unsigned* __restrict__ F, int n) {
  int i = blockIdx.x * 256 + threadIdx.x;
  int stride = gridDim.x * 256;
  for (; i < n; i += stride) F[i] = SENT;
}

__global__ __launch_bounds__(320) void fused(
    const float* __restrict__ qp,
    const float* __restrict__ nr, const float* __restrict__ qsr,
    const float* __restrict__ len, const float* __restrict__ slp,
    const float* __restrict__ twp, const float* __restrict__ ssp,
    const float* __restrict__ xsp,
    float* __restrict__ S1, float* __restrict__ S2,
    float* __restrict__ out) {
  const int wave = threadIdx.x >> 6;
  const int lane = threadIdx.x & 63;
  if (wave < 4) {
    run_A(qp, nr, qsr, len, slp, twp, ssp, xsp, S1,
          (blockIdx.x << 2) + wave, lane);
  } else if (blockIdx.x < 16) {
    run_B(qp, nr, qsr, len, slp, twp, ssp, xsp, S1, S2, blockIdx.x, lane);
  } else if (blockIdx.x == 16) {
    run_C(qp, nr, qsr, len, slp, twp, ssp, xsp, S2, out, lane);
  }
}

extern "C" void kernel_launch(void* const* d_in, const int* in_sizes, int n_in,
                              void* d_out, int out_size, void* d_ws, size_t ws_size,
                              hipStream_t stream) {
  const float* q_prime = (const float*)d_in[0];
  const float* n_raw   = (const float*)d_in[1];
  const float* qs_raw  = (const float*)d_in[2];
  const float* length  = (const float*)d_in[3];
  const float* slope   = (const float*)d_in[4];
  const float* tw      = (const float*)d_in[5];
  const float* ss      = (const float*)d_in[6];
  const float* xs      = (const float*)d_in[7];
  float* out = (float*)d_out;
  float* S1 = (float*)d_ws;                    // 337 x 1024 level-6 series (sentinel-init)
  float* S2 = S1 + 337 * 1024;                 // 337 x 16 level-12 series (sentinel-init)
  const int nsent = 337 * 1024 + 337 * 16;
  kinit<<<128, 256, 0, stream>>>((unsigned*)d_ws, nsent);
  fused<<<256, 320, 0, stream>>>(q_prime, n_raw, qs_raw, length, slope, tw, ss, xs,
                                 S1, S2, out);
}